// Round 5
// baseline (470.423 us; speedup 1.0000x reference)
//
#include <hip/hip_runtime.h>
#include <math.h>

#define Bv   64
#define Nv   900
#define Mv   64
#define NCls 128
#define NCOLS (Nv + 1)          // 901 columns incl. dummy col 0
#define KREG 15                 // columns per lane: j = t + 64k, k=0..14
#define INFV 1000000000.0f

// uniform dynamic read of a constant-indexed register array (stays in VGPRs)
#define SEL15(arr, kidx, dst) do {            \
    int _s = arr[0];                          \
    _Pragma("unroll")                         \
    for (int _kk = 1; _kk < KREG; _kk++)      \
        _s = ((kidx) == _kk) ? arr[_kk] : _s; \
    (dst) = _s;                               \
} while (0)

// uniform dynamic write (lane-targeted, register-indexed by uniform kidx)
#define SET15(arr, kidx, val) do {            \
    _Pragma("unroll")                         \
    for (int _kk = 0; _kk < KREG; _kk++)      \
        if ((kidx) == _kk) arr[_kk] = (val);  \
} while (0)

// ---------------------------------------------------------------------------
// Kernel 1: cost C[b][n][m] — R3's known-good one-wave-per-(b,n) version.
// ---------------------------------------------------------------------------
__global__ __launch_bounds__(64) void cost_kernel(
    const float* __restrict__ logits,   // [B,N,128]
    const float* __restrict__ corners,  // [B,N,8,3]
    const int*   __restrict__ labels,   // [B,64]
    const float* __restrict__ boxes,    // [B,64,7]
    float*       __restrict__ C)        // [B,N,64]
{
    const int n = blockIdx.x, b = blockIdx.y, t = threadIdx.x;
    const long bn = (long)b * Nv + n;

    // softmax numerators: lane t handles classes 2t,2t+1 (no max-sub; |logits|<~6)
    const float2 l2 = ((const float2*)(logits + bn * NCls))[t];
    float e0 = expf(l2.x), e1 = expf(l2.y);

    __shared__ float probs[NCls];
    ((float2*)probs)[t] = make_float2(e0, e1);

    float s = e0 + e1;
    #pragma unroll
    for (int off = 1; off < 64; off <<= 1) s += __shfl_xor(s, off, 64);

    // center = mean over 8 corners
    const float* cp = corners + bn * 24;
    float cx = 0.f, cy = 0.f, cz = 0.f;
    if (t < 8) { cx = cp[3 * t]; cy = cp[3 * t + 1]; cz = cp[3 * t + 2]; }
    #pragma unroll
    for (int off = 1; off < 8; off <<= 1) {
        cx += __shfl_xor(cx, off, 64);
        cy += __shfl_xor(cy, off, 64);
        cz += __shfl_xor(cz, off, 64);
    }
    cx = __shfl(cx, 0, 64) * 0.125f;
    cy = __shfl(cy, 0, 64) * 0.125f;
    cz = __shfl(cz, 0, 64) * 0.125f;

    __syncthreads();   // probs visible

    int lbl = labels[b * Mv + t];
    float pm = probs[lbl] / s;
    const float* bx = boxes + ((long)b * Mv + t) * 7;
    float dx = cx - bx[0], dy = cy - bx[1], dz = cz - bx[2];
    float d = sqrtf(dx * dx + dy * dy + dz * dz);

    C[bn * Mv + t] = 5.0f * d - pm;
}

// ---------------------------------------------------------------------------
// Kernel 2: transpose C[B,900,64] -> CT[B,64,900] (known good from R2)
// ---------------------------------------------------------------------------
__global__ __launch_bounds__(256) void transpose_kernel(
    const float* __restrict__ C, float* __restrict__ CT)
{
    __shared__ float tile[64][65];
    const int b  = blockIdx.y;
    const int n0 = blockIdx.x * 64;
    const int t  = threadIdx.x;
    const int c  = t & 63;
    const int r4 = t >> 6;

    #pragma unroll
    for (int i = 0; i < 16; i++) {
        int r = r4 + i * 4;              // n within tile
        int n = n0 + r;
        if (n < Nv) tile[r][c] = C[((long)b * Nv + n) * Mv + c];
    }
    __syncthreads();
    #pragma unroll
    for (int i = 0; i < 16; i++) {
        int r = r4 + i * 4;              // m
        int n = n0 + c;
        if (n < Nv) CT[((long)b * Mv + r) * Nv + n] = tile[c][r];
    }
}

// ---------------------------------------------------------------------------
// Kernel 3: LSA — EXACTLY R3's passing solver (u=rowmin, v=0 duals), with the
// single change that Phase C reads mat (CT: rs=900, cs=1 -> coalesced rows).
// ---------------------------------------------------------------------------
__global__ __launch_bounds__(64) void lsa_kernel(
    const float* __restrict__ C,      // [B,N,M] — Phase A scans (coalesced)
    const float* __restrict__ mat,    // Phase C matrix (CT or C), batch stride 57600
    long rs, long cs,                 // row/col strides of mat
    float* __restrict__ outPred, float* __restrict__ outTgt)
{
    const int b = blockIdx.x;
    const int t = threadIdx.x;
    const float* cb = C   + (size_t)b * Nv * Mv;
    const float* mb = mat + (size_t)b * Nv * Mv;

    // ---- Phase A: row argmin (lane t = row t+1); 4 disjoint ranges for ILP
    float mv0 = INFV, mv1 = INFV, mv2 = INFV, mv3 = INFV;
    int   mj0 = 0,    mj1 = 0,    mj2 = 0,    mj3 = 0;
    #pragma unroll 5
    for (int n = 0; n < 225; ++n) {
        float c0 = cb[(size_t)(n      ) * Mv + t];
        float c1 = cb[(size_t)(n + 225) * Mv + t];
        float c2 = cb[(size_t)(n + 450) * Mv + t];
        float c3 = cb[(size_t)(n + 675) * Mv + t];
        if (c0 < mv0) { mv0 = c0; mj0 = n;       }
        if (c1 < mv1) { mv1 = c1; mj1 = n + 225; }
        if (c2 < mv2) { mv2 = c2; mj2 = n + 450; }
        if (c3 < mv3) { mv3 = c3; mj3 = n + 675; }
    }
    float rowmin = mv0; int rown = mj0;   // ordered merge: first index wins ties
    if (mv1 < rowmin) { rowmin = mv1; rown = mj1; }
    if (mv2 < rowmin) { rowmin = mv2; rown = mj2; }
    if (mv3 < rowmin) { rowmin = mv3; rown = mj3; }

    float u_reg = rowmin;            // lane l holds u[l+1]
    const int jcol = rown + 1;       // chosen column 1..900

    // ---- Phase B: duplicate detection (first occurrence wins)
    bool isdup = false;
    #pragma unroll
    for (int s = 1; s < 64; ++s) {
        int oj = __shfl(jcol, (t + 64 - s) & 63, 64);
        isdup |= (oj == jcol) && (s <= t);
    }
    unsigned long long pending = __ballot(isdup);

    int   p_reg[KREG], way_reg[KREG];
    float v_reg[KREG], minv[KREG];
    #pragma unroll
    for (int k = 0; k < KREG; k++) { p_reg[k] = 0; way_reg[k] = 0; v_reg[k] = 0.f; }

    int rowcol = isdup ? 0 : jcol;   // lane i: column assigned to row i+1

    // scatter winners into distributed p[]
    #pragma unroll 8
    for (int i = 0; i < 64; ++i) {
        int jb = __shfl(jcol, i, 64);
        if (!((pending >> i) & 1ull) && t == (jb & 63))
            SET15(p_reg, jb >> 6, i + 1);
    }

    // ---- Phase C: Dijkstra phases for conflicted rows only
    while (pending) {
        const int i1v = __ffsll(pending);    // row index (1-based)
        pending &= pending - 1;

        unsigned int usedMask = 0;
        unsigned long long rowMask = 0;
        #pragma unroll
        for (int k = 0; k < KREG; k++) minv[k] = INFV;

        int j0 = 0;
        int i0 = i1v;
        while (true) {
            if ((j0 & 63) == t) usedMask |= 1u << (j0 >> 6);
            rowMask |= 1ull << (i0 - 1);
            const float u_i0 = __shfl(u_reg, i0 - 1, 64);
            const float* rb = mb + (size_t)(i0 - 1) * rs;

            float bestv = INFV;
            int   bestj = NCOLS;
            #pragma unroll
            for (int k = 0; k < KREG; k++) {
                int j = t + (k << 6);
                if (j < NCOLS) {
                    float c   = (j == 0) ? 0.0f : rb[(size_t)(j - 1) * cs];
                    float cur = (c - u_i0) - v_reg[k];
                    bool used = (usedMask >> k) & 1u;
                    if (!used && cur < minv[k]) { minv[k] = cur; way_reg[k] = j0; }
                    float mval = used ? INFV : minv[k];
                    if (mval < bestv) { bestv = mval; bestj = j; }
                }
            }
            #pragma unroll
            for (int off = 1; off < 64; off <<= 1) {
                float ov = __shfl_xor(bestv, off, 64);
                int   oj = __shfl_xor(bestj, off, 64);
                if (ov < bestv || (ov == bestv && oj < bestj)) { bestv = ov; bestj = oj; }
            }
            const float delta = bestv;

            if ((rowMask >> t) & 1ull) u_reg += delta;
            #pragma unroll
            for (int k = 0; k < KREG; k++) {
                if ((usedMask >> k) & 1u) v_reg[k] -= delta;
                else                      minv[k] -= delta;
            }

            j0 = bestj;
            const int k0 = j0 >> 6, l0 = j0 & 63;
            int ptmp; SEL15(p_reg, k0, ptmp);
            i0 = __shfl(ptmp, l0, 64);
            if (i0 == 0) break;              // free column reached
        }

        // backtrack: reassign columns along augmenting path
        while (j0 != 0) {
            const int k0 = j0 >> 6, l0 = j0 & 63;
            int wtmp; SEL15(way_reg, k0, wtmp);
            const int jprev = __shfl(wtmp, l0, 64);
            int pv;
            if (jprev == 0) {
                pv = i1v;
            } else {
                int ptmp; SEL15(p_reg, jprev >> 6, ptmp);
                pv = __shfl(ptmp, jprev & 63, 64);
            }
            if (t == l0) SET15(p_reg, k0, pv);
            if (t == pv - 1) rowcol = j0;    // row->column mirror
            j0 = jprev;
        }
    }

    outPred[b * Mv + t] = (float)(rowcol - 1);
    outTgt[b * Mv + t]  = (float)t;
}

// ---------------------------------------------------------------------------
extern "C" void kernel_launch(void* const* d_in, const int* in_sizes, int n_in,
                              void* d_out, int out_size, void* d_ws, size_t ws_size,
                              hipStream_t stream)
{
    (void)in_sizes; (void)n_in; (void)out_size;

    const float* logits  = (const float*)d_in[0];   // [64,900,128] f32
    const float* corners = (const float*)d_in[1];   // [64,900,8,3] f32
    const int*   labels  = (const int*)  d_in[2];   // [64,64] i32
    const float* boxes   = (const float*)d_in[3];   // [64,64,7] f32

    float* out  = (float*)d_out;
    float* Cc   = out;                               // [64,900,64]
    float* pred = out + (size_t)Bv * Nv * Mv;        // [64,64] as f32
    float* tgt  = pred + (size_t)Bv * Mv;            // [64,64] as f32

    cost_kernel<<<dim3(Nv, Bv), 64, 0, stream>>>(logits, corners, labels, boxes, Cc);

    const size_t ctBytes = (size_t)Bv * Mv * Nv * sizeof(float);
    if (ws_size >= ctBytes) {
        float* CT = (float*)d_ws;                    // [64,64,900]
        transpose_kernel<<<dim3((Nv + 63) / 64, Bv), 256, 0, stream>>>(Cc, CT);
        lsa_kernel<<<Bv, 64, 0, stream>>>(Cc, CT, (long)Nv, 1L, pred, tgt);
    } else {
        // no workspace: strided Phase C reads from C — R3 behavior, correct
        lsa_kernel<<<Bv, 64, 0, stream>>>(Cc, Cc, 1L, (long)Mv, pred, tgt);
    }
}